// Round 1
// 296.765 us; speedup vs baseline: 1.0459x; 1.0459x over previous
//
#include <hip/hip_runtime.h>

// ---------------- problem constants ----------------
#define NUM_GRAPHS 64
#define NODE_SZ    200
#define FEAT       200
#define HID        256
#define HALF       128
#define N_NODES    (NUM_GRAPHS * NODE_SZ)   // 12800
#define KREAD      (NODE_SZ * HID)          // 51200
#define HBLK       128                      // histogram/scatter blocks

typedef unsigned short ushort_t;
typedef unsigned int uint_t;
typedef __attribute__((ext_vector_type(8))) short bf16x8;
typedef __attribute__((ext_vector_type(4))) float f32x4;

#define GAS(p) ((const __attribute__((address_space(1))) void*)(p))
#define LAS(p) ((__attribute__((address_space(3))) void*)(p))

__device__ __forceinline__ float bf2f(ushort_t u) {
    union { unsigned int i; float f; } v; v.i = ((unsigned int)u) << 16; return v.f;
}
__device__ __forceinline__ ushort_t f2bf(float f) {
    union { float f; unsigned int i; } v; v.f = f;
    unsigned int x = v.i;
    unsigned int r = (x + 0x7fffu + ((x >> 16) & 1u)) >> 16;  // RNE
    return (ushort_t)r;
}

// ---------------- CSR build (no global atomics) ----------------
__global__ __launch_bounds__(1024) void bhist_kernel(const int* __restrict__ ei,
                                                     const float* __restrict__ ew,
                                                     uint_t* __restrict__ bh, int E) {
    __shared__ uint_t h[N_NODES];
    for (int i = threadIdx.x; i < N_NODES; i += 1024) h[i] = 0;
    __syncthreads();
    int b = blockIdx.x;
    int epb = (E + HBLK - 1) / HBLK;
    int e0 = b * epb, e1 = min(e0 + epb, E);
    for (int e = e0 + threadIdx.x; e < e1; e += 1024) {
        int dst = ei[E + e];
        float w = ew[e];
        if (w > 0.0f)      atomicAdd(&h[dst], 1u);
        else if (w < 0.0f) atomicAdd(&h[dst], 0x10000u);
    }
    __syncthreads();
    uint_t* out = bh + (size_t)b * N_NODES;
    for (int i = threadIdx.x * 4; i < N_NODES; i += 4096)
        *(uint4*)&out[i] = *(const uint4*)&h[i];
}

// Column prefix over the block-histograms; ILP-8 batched loads (latency hiding).
__global__ void colpref_kernel(uint_t* __restrict__ bh, int* __restrict__ counts,
                               int* __restrict__ cnt_p) {
    int n = blockIdx.x * 256 + threadIdx.x;
    if (n >= N_NODES) return;
    uint_t seq = 0;
#pragma unroll 1
    for (int b = 0; b < HBLK; b += 8) {
        uint_t v[8];
#pragma unroll
        for (int j = 0; j < 8; ++j) v[j] = bh[(size_t)(b + j) * N_NODES + n];
#pragma unroll
        for (int j = 0; j < 8; ++j) {
            bh[(size_t)(b + j) * N_NODES + n] = seq;
            seq += v[j];
        }
    }
    counts[n] = (int)((seq & 0xffffu) + (seq >> 16));
    cnt_p[n]  = (int)(seq & 0xffffu);
}

__global__ __launch_bounds__(1024) void scan_kernel(const int* __restrict__ counts,
                                                    const int* __restrict__ cnt_p,
                                                    uint2* __restrict__ obnd, int n) {
    const int PER = 13;
    int t = threadIdx.x;
    int start = t * PER;
    int local[PER];
    int sum = 0;
#pragma unroll
    for (int i = 0; i < PER; ++i) {
        int idx = start + i;
        int v = (idx < n) ? counts[idx] : 0;
        local[i] = sum;
        sum += v;
    }
    int lane = t & 63, wid = t >> 6;
    int inc = sum;
#pragma unroll
    for (int d = 1; d < 64; d <<= 1) {
        int up = __shfl_up(inc, d);
        if (lane >= d) inc += up;
    }
    __shared__ int wsum[16], woff[16];
    if (lane == 63) wsum[wid] = inc;
    __syncthreads();
    if (t < 16) {
        int acc = 0;
        for (int j = 0; j < 16; ++j) if (j < t) acc += wsum[j];
        woff[t] = acc;
    }
    __syncthreads();
    int base = woff[wid] + (inc - sum);
#pragma unroll
    for (int i = 0; i < PER; ++i) {
        int idx = start + i;
        if (idx < n) {
            uint_t off = (uint_t)(base + local[i]);
            obnd[idx] = make_uint2(off, off + (uint_t)cnt_p[idx]);
        }
    }
    if (t == 1023) {
        uint_t tot = (uint_t)(base + sum);
        obnd[n] = make_uint2(tot, tot);
    }
}

// ---------------- scatter + all casts, one launch ----------------
// blocks [0,128): scatter; [128,512): weight rearrange+cast; [512,1312): x cast (pad to 256).
// Weight layout per layer (wall, [512 x 256] bf16):
//   rows   0..127 : Wp[:, :K]   (agg-side, "left")
//   rows 128..255 : Wn[:, :K]
//   rows 256..383 : Wp[:, K:2K] (self-side, "right")
//   rows 384..511 : Wn[:, K:2K]
// K=200 for layer 0 (cols 200..255 zero), K=256 for layers 1,2.
__global__ __launch_bounds__(1024) void scat_prep_kernel(
        const int* __restrict__ ei, const float* __restrict__ ew,
        const uint_t* __restrict__ bh, const uint2* __restrict__ obnd,
        uint2* __restrict__ es, int E,
        const float* __restrict__ W0p, const float* __restrict__ W0n,
        const float* __restrict__ W1p, const float* __restrict__ W1n,
        const float* __restrict__ W2p, const float* __restrict__ W2n,
        const float* __restrict__ x,
        ushort_t* __restrict__ wall, ushort_t* __restrict__ xb) {
    __shared__ uint_t cur[N_NODES];
    int bx = blockIdx.x;
    if (bx < HBLK) {
        const uint_t* pref = bh + (size_t)bx * N_NODES;
        for (int i = threadIdx.x * 4; i < N_NODES; i += 4096)
            *(uint4*)&cur[i] = *(const uint4*)&pref[i];
        __syncthreads();
        int epb = (E + HBLK - 1) / HBLK;
        int e0 = bx * epb, e1 = min(e0 + epb, E);
        for (int e = e0 + threadIdx.x; e < e1; e += 1024) {
            int src = ei[e];
            int dst = ei[E + e];
            float w = ew[e];
            if (w > 0.0f) {
                uint_t old = atomicAdd(&cur[dst], 1u);
                uint_t pos = obnd[dst].x + (old & 0xffffu);
                es[pos] = make_uint2((uint_t)src, __float_as_uint(w));
            } else if (w < 0.0f) {
                uint_t old = atomicAdd(&cur[dst], 0x10000u);
                uint_t pos = obnd[dst].y + (old >> 16);
                es[pos] = make_uint2((uint_t)src, __float_as_uint(-w));
            }
        }
    } else if (bx < 512) {
        int idx = (bx - 128) * 1024 + threadIdx.x;      // < 3*131072
        int layer = idx >> 17;
        int within = idx & 131071;
        int rr = within >> 8;                            // 0..511
        int col = within & 255;
        const float* Wp = (layer == 0) ? W0p : (layer == 1) ? W1p : W2p;
        const float* Wn = (layer == 0) ? W0n : (layer == 1) ? W1n : W2n;
        int Ks = (layer == 0) ? 200 : 256;
        int q = rr >> 7;                                 // 0:Pl 1:Nl 2:Pr 3:Nr
        const float* Wsrc = (q & 1) ? Wn : Wp;
        int row = rr & 127;
        int scol = col + ((q >> 1) ? Ks : 0);
        float v = (col < Ks) ? Wsrc[(size_t)row * (2 * Ks) + scol] : 0.0f;
        wall[idx] = f2bf(v);
    } else {
        int idx = (bx - 512) * 1024 + threadIdx.x;       // < 12800*64
        int n = idx >> 6;
        int c0 = (idx & 63) * 4;
        ushort4 o = {0, 0, 0, 0};
        if (c0 < 200) {
            float4 v = *(const float4*)&x[(size_t)n * 200 + c0];
            o.x = f2bf(v.x); o.y = f2bf(v.y); o.z = f2bf(v.z); o.w = f2bf(v.w);
        }
        *(ushort4*)&xb[(size_t)n * 256 + c0] = o;
    }
}

// ---------------- per-layer GEMM: Yall = h @ wall^T  ([12800x256] x [512x256]^T) ----------------
// block = 32 M x 128 N, 4 waves (wave = 32 N-cols x 32 M-rows), grid (400, 4), dbuf LDS.
template <int KSTEPS>
__global__ __launch_bounds__(256) void gemm_mfma(
        const ushort_t* __restrict__ A,    // [12800 x 256] bf16
        const ushort_t* __restrict__ B,    // [512 x 256] bf16 (wall layer)
        ushort_t* __restrict__ Y) {        // [12800 x 512] bf16
    __shared__ __align__(16) ushort_t As[2][32 * 32];    // 2 x 2 KB
    __shared__ __align__(16) ushort_t Bs[2][128 * 32];   // 2 x 8 KB
    int mBase = blockIdx.x * 32;
    int nBase = blockIdx.y * 128;
    int tid  = threadIdx.x;
    int lane = tid & 63;
    int wv   = tid >> 6;
    int r    = lane & 15;
    int quad = lane >> 4;

    int rowA = tid >> 2, colA = (tid & 3) * 8;           // A valid for tid < 128 (rows 0..31)
    const ushort_t* gA  = A + (size_t)(mBase + (rowA & 31)) * 256 + colA;
    const ushort_t* gB0 = B + (size_t)(nBase + rowA) * 256 + colA;
    const ushort_t* gB1 = B + (size_t)(nBase + rowA + 64) * 256 + colA;

    f32x4 acc00 = {0.f,0.f,0.f,0.f}, acc01 = {0.f,0.f,0.f,0.f};
    f32x4 acc10 = {0.f,0.f,0.f,0.f}, acc11 = {0.f,0.f,0.f,0.f};

    if (tid < 128)
        __builtin_amdgcn_global_load_lds(GAS(gA), LAS(&As[0][wv * 512]), 16, 0, 0);
    __builtin_amdgcn_global_load_lds(GAS(gB0), LAS(&Bs[0][wv * 512]), 16, 0, 0);
    __builtin_amdgcn_global_load_lds(GAS(gB1), LAS(&Bs[0][2048 + wv * 512]), 16, 0, 0);

    for (int kt = 0; kt < KSTEPS; ++kt) {
        int cur = kt & 1;
        __syncthreads();
        if (kt + 1 < KSTEPS) {
            int kB = (kt + 1) * 32;
            if (tid < 128)
                __builtin_amdgcn_global_load_lds(GAS(gA + kB), LAS(&As[cur ^ 1][wv * 512]), 16, 0, 0);
            __builtin_amdgcn_global_load_lds(GAS(gB0 + kB), LAS(&Bs[cur ^ 1][wv * 512]), 16, 0, 0);
            __builtin_amdgcn_global_load_lds(GAS(gB1 + kB), LAS(&Bs[cur ^ 1][2048 + wv * 512]), 16, 0, 0);
        }
        bf16x8 a0 = *(const bf16x8*)&As[cur][r * 32 + quad * 8];
        bf16x8 a1 = *(const bf16x8*)&As[cur][(16 + r) * 32 + quad * 8];
        bf16x8 b0 = *(const bf16x8*)&Bs[cur][(wv * 32 + r) * 32 + quad * 8];
        bf16x8 b1 = *(const bf16x8*)&Bs[cur][(wv * 32 + 16 + r) * 32 + quad * 8];
        acc00 = __builtin_amdgcn_mfma_f32_16x16x32_bf16(a0, b0, acc00, 0, 0, 0);
        acc01 = __builtin_amdgcn_mfma_f32_16x16x32_bf16(a0, b1, acc01, 0, 0, 0);
        acc10 = __builtin_amdgcn_mfma_f32_16x16x32_bf16(a1, b0, acc10, 0, 0, 0);
        acc11 = __builtin_amdgcn_mfma_f32_16x16x32_bf16(a1, b1, acc11, 0, 0, 0);
    }
#pragma unroll
    for (int jn = 0; jn < 2; ++jn) {
        int cl = nBase + wv * 32 + jn * 16 + r;
        f32x4 am0 = jn ? acc01 : acc00;
        f32x4 am1 = jn ? acc11 : acc10;
#pragma unroll
        for (int reg = 0; reg < 4; ++reg) {
            int m0 = mBase + quad * 4 + reg;
            Y[(size_t)m0 * 512 + cl]        = f2bf(am0[reg]);
            Y[(size_t)(m0 + 16) * 512 + cl] = f2bf(am1[reg]);
        }
    }
}

// ---------------- aggregate projected rows + combine: h_out = aggY/deg + Z + bias (+leaky) ----
// one node per wave, 4 waves/block; gathers 128-wide bf16 rows (4 B/lane/edge), ILP-8.
template <bool LEAKY>
__global__ __launch_bounds__(256) void aggcomb_kernel(
        const ushort_t* __restrict__ Y,      // [12800 x 512]: Yp | Yn | Zp | Zn
        const uint2* __restrict__ obnd,
        const uint2* __restrict__ es,
        const float* __restrict__ bp, const float* __restrict__ bn,
        ushort_t* __restrict__ out) {        // [12800 x 256]
    int lane = threadIdx.x & 63;
    int wv   = threadIdx.x >> 6;
    int n = blockIdx.x * 4 + wv;
    int c0 = lane * 2;                       // 2 cols per lane, 0..127
    uint2 ob = obnd[n];
    uint_t off = ob.x, mid = ob.y, end = obnd[n + 1].x;

    float accp[2] = {0.f, 0.f};
    float accn[2] = {0.f, 0.f};

#pragma unroll 1
    for (int phase = 0; phase < 2; ++phase) {
        uint_t lo = phase ? mid : off;
        uint_t hi = phase ? end : mid;
        float* acc = phase ? accn : accp;
        const ushort_t* Yb = Y + (phase ? 128 : 0) + c0;
#pragma unroll 1
        for (uint_t base = lo; base < hi; base += 64) {
            int cnt = (int)min(64u, hi - base);
            uint2 rec = es[base + (uint_t)min(lane, cnt - 1)];
            int i = 0;
#pragma unroll 1
            for (; i + 8 <= cnt; i += 8) {
                int s[8]; float w[8]; uint_t u[8];
#pragma unroll
                for (int j = 0; j < 8; ++j) {
                    s[j] = __shfl((int)rec.x, i + j);
                    w[j] = __uint_as_float((uint_t)__shfl((int)rec.y, i + j));
                }
#pragma unroll
                for (int j = 0; j < 8; ++j) u[j] = *(const uint_t*)&Yb[(size_t)s[j] * 512];
#pragma unroll
                for (int j = 0; j < 8; ++j) {
                    acc[0] = fmaf(w[j], bf2f((ushort_t)(u[j] & 0xffffu)), acc[0]);
                    acc[1] = fmaf(w[j], bf2f((ushort_t)(u[j] >> 16)), acc[1]);
                }
            }
#pragma unroll 1
            for (; i < cnt; ++i) {
                int s = __shfl((int)rec.x, i);
                float w = __uint_as_float((uint_t)__shfl((int)rec.y, i));
                uint_t u = *(const uint_t*)&Yb[(size_t)s * 512];
                acc[0] = fmaf(w, bf2f((ushort_t)(u & 0xffffu)), acc[0]);
                acc[1] = fmaf(w, bf2f((ushort_t)(u >> 16)), acc[1]);
            }
        }
    }

    float dp = fmaxf((float)(mid - off), 1.0f);
    float dn = fmaxf((float)(end - mid), 1.0f);
    float rp = 1.0f / dp, rn = 1.0f / dn;
    uint_t zp = *(const uint_t*)&Y[(size_t)n * 512 + 256 + c0];
    uint_t zn = *(const uint_t*)&Y[(size_t)n * 512 + 384 + c0];
    float vp0 = fmaf(accp[0], rp, bf2f((ushort_t)(zp & 0xffffu)) + bp[c0]);
    float vp1 = fmaf(accp[1], rp, bf2f((ushort_t)(zp >> 16))     + bp[c0 + 1]);
    float vn0 = fmaf(accn[0], rn, bf2f((ushort_t)(zn & 0xffffu)) + bn[c0]);
    float vn1 = fmaf(accn[1], rn, bf2f((ushort_t)(zn >> 16))     + bn[c0 + 1]);
    if (LEAKY) {
        vp0 = (vp0 > 0.0f) ? vp0 : 0.01f * vp0;
        vp1 = (vp1 > 0.0f) ? vp1 : 0.01f * vp1;
        vn0 = (vn0 > 0.0f) ? vn0 : 0.01f * vn0;
        vn1 = (vn1 > 0.0f) ? vn1 : 0.01f * vn1;
    }
    uint_t op = (uint_t)f2bf(vp0) | ((uint_t)f2bf(vp1) << 16);
    uint_t on = (uint_t)f2bf(vn0) | ((uint_t)f2bf(vn1) << 16);
    *(uint_t*)&out[(size_t)n * 256 + c0]       = op;
    *(uint_t*)&out[(size_t)n * 256 + 128 + c0] = on;
}

// ---------------- readout via MFMA, split-K partials (no atomics) ----------------
__global__ __launch_bounds__(256) void readout_mfma(
        const ushort_t* __restrict__ h, const float* __restrict__ Wr,
        float* __restrict__ partial) {
    __shared__ __align__(16) ushort_t As[64 * 32];
    __shared__ __align__(16) ushort_t Bs[64 * 32];
    int nBase  = blockIdx.x * 64;
    int kStart = blockIdx.y * 800;
    int tid  = threadIdx.x;
    int lane = tid & 63;
    int wv   = tid >> 6;
    int r    = lane & 15;
    int quad = lane >> 4;

    f32x4 acc[4];
#pragma unroll
    for (int j = 0; j < 4; ++j) acc[j] = (f32x4){0.f, 0.f, 0.f, 0.f};

    for (int kt = 0; kt < 25; ++kt) {
        int kBase = kStart + kt * 32;
        int lin = tid * 8;
        int row = lin >> 5, col = lin & 31;
        *(uint4*)&As[lin] = *(const uint4*)&h[(size_t)row * KREAD + kBase + col];
        {
            const float* wp = &Wr[(size_t)(nBase + row) * KREAD + kBase + col];
            float4 f0 = *(const float4*)&wp[0];
            float4 f1 = *(const float4*)&wp[4];
            ushort4 b0, b1;
            b0.x = f2bf(f0.x); b0.y = f2bf(f0.y); b0.z = f2bf(f0.z); b0.w = f2bf(f0.w);
            b1.x = f2bf(f1.x); b1.y = f2bf(f1.y); b1.z = f2bf(f1.z); b1.w = f2bf(f1.w);
            *(ushort4*)&Bs[lin]     = b0;
            *(ushort4*)&Bs[lin + 4] = b1;
        }
        __syncthreads();
        bf16x8 a = *(const bf16x8*)&As[(wv * 16 + r) * 32 + quad * 8];
#pragma unroll
        for (int j = 0; j < 4; ++j) {
            bf16x8 b = *(const bf16x8*)&Bs[(j * 16 + r) * 32 + quad * 8];
            acc[j] = __builtin_amdgcn_mfma_f32_16x16x32_bf16(a, b, acc[j], 0, 0, 0);
        }
        __syncthreads();
    }
    float* out = partial + (size_t)blockIdx.y * (64 * HID);
#pragma unroll
    for (int j = 0; j < 4; ++j) {
        int c = nBase + j * 16 + r;
#pragma unroll
        for (int reg = 0; reg < 4; ++reg) {
            int g = wv * 16 + quad * 4 + reg;
            out[g * HID + c] = acc[j][reg];
        }
    }
}

// ---------------- final: fold 64 partials, dot with Wl ----------------
__global__ void final_kernel(const float* __restrict__ partial, const float* __restrict__ br,
                             const float* __restrict__ Wl, const float* __restrict__ bl,
                             float* __restrict__ out) {
    int g = blockIdx.x;
    int c = threadIdx.x;   // 256
    float s = 0.0f;
#pragma unroll 4
    for (int k = 0; k < 64; ++k) s += partial[(size_t)k * (64 * HID) + g * HID + c];
    float v = (s + br[c]) * Wl[c];
#pragma unroll
    for (int d = 32; d > 0; d >>= 1) v += __shfl_down(v, d);
    __shared__ float sh[4];
    if ((c & 63) == 0) sh[c >> 6] = v;
    __syncthreads();
    if (c == 0) out[g] = sh[0] + sh[1] + sh[2] + sh[3] + bl[0];
}

// ---------------- launch ----------------
extern "C" void kernel_launch(void* const* d_in, const int* in_sizes, int n_in,
                              void* d_out, int out_size, void* d_ws, size_t ws_size,
                              hipStream_t stream) {
    const float* x  = (const float*)d_in[0];
    const int*   ei = (const int*)d_in[1];
    const float* ew = (const float*)d_in[2];
    const float* Wp0 = (const float*)d_in[4];
    const float* bp0 = (const float*)d_in[5];
    const float* Wn0 = (const float*)d_in[6];
    const float* bn0 = (const float*)d_in[7];
    const float* Wp1 = (const float*)d_in[8];
    const float* bp1 = (const float*)d_in[9];
    const float* Wn1 = (const float*)d_in[10];
    const float* bn1 = (const float*)d_in[11];
    const float* Wp2 = (const float*)d_in[12];
    const float* bp2 = (const float*)d_in[13];
    const float* Wn2 = (const float*)d_in[14];
    const float* bn2 = (const float*)d_in[15];
    const float* Wr  = (const float*)d_in[16];
    const float* br  = (const float*)d_in[17];
    const float* Wl  = (const float*)d_in[18];
    const float* bl  = (const float*)d_in[19];
    const int E = in_sizes[1] / 2;   // 409600

    // ---- workspace layout (bytes) ----
    char* ws = (char*)d_ws;
    float*    partial = (float*)(ws + 0);             // 64*64*256 fp32 = 4194304
    uint_t*   bh      = (uint_t*)(ws + 4194304);      // 128*12800*4 -> 10747904
    int*      counts  = (int*)(ws + 10747904);        // -> 10799104
    int*      cnt_p   = (int*)(ws + 10799104);        // -> 10850304
    uint2*    obnd    = (uint2*)(ws + 10850304);      // -> 10952768 (padded)
    uint2*    es      = (uint2*)(ws + 10952768);      // E*8 -> 14229568
    ushort_t* Yall    = (ushort_t*)(ws + 14229568);   // 12800*512 bf16 -> 27336768
    ushort_t* hA      = (ushort_t*)(ws + 27336768);   // 12800*256 bf16 -> 33890368
    ushort_t* hB      = (ushort_t*)(ws + 33890368);   // -> 40443968
    ushort_t* wall    = (ushort_t*)(ws + 40443968);   // 3*512*256 bf16 -> 41230400
    ushort_t* xb      = (ushort_t*)(ws + 41230400);   // 12800*256 bf16 -> 47784000

    // CSR build
    hipLaunchKernelGGL(bhist_kernel, dim3(HBLK), dim3(1024), 0, stream, ei, ew, bh, E);
    hipLaunchKernelGGL(colpref_kernel, dim3((N_NODES + 255) / 256), dim3(256), 0, stream,
                       bh, counts, cnt_p);
    hipLaunchKernelGGL(scan_kernel, dim3(1), dim3(1024), 0, stream, counts, cnt_p, obnd, N_NODES);
    // scatter + weight rearrange + x cast in one launch
    hipLaunchKernelGGL(scat_prep_kernel, dim3(1312), dim3(1024), 0, stream,
                       ei, ew, bh, obnd, es, E,
                       Wp0, Wn0, Wp1, Wn1, Wp2, Wn2, x, wall, xb);

    // layer 0: K=200 (padded to 224 via 7 K-steps)
    hipLaunchKernelGGL((gemm_mfma<7>), dim3(N_NODES / 32, 4), dim3(256), 0, stream,
                       xb, wall + 0 * 131072, Yall);
    hipLaunchKernelGGL((aggcomb_kernel<true>), dim3(N_NODES / 4), dim3(256), 0, stream,
                       Yall, obnd, es, bp0, bn0, hA);
    // layer 1: K=256
    hipLaunchKernelGGL((gemm_mfma<8>), dim3(N_NODES / 32, 4), dim3(256), 0, stream,
                       hA, wall + 1 * 131072, Yall);
    hipLaunchKernelGGL((aggcomb_kernel<true>), dim3(N_NODES / 4), dim3(256), 0, stream,
                       Yall, obnd, es, bp1, bn1, hB);
    // layer 2: K=256, no leaky
    hipLaunchKernelGGL((gemm_mfma<8>), dim3(N_NODES / 32, 4), dim3(256), 0, stream,
                       hB, wall + 2 * 131072, Yall);
    hipLaunchKernelGGL((aggcomb_kernel<false>), dim3(N_NODES / 4), dim3(256), 0, stream,
                       Yall, obnd, es, bp2, bn2, hA);

    // readout + final
    hipLaunchKernelGGL(readout_mfma, dim3(4, 64), dim3(256), 0, stream, hA, Wr, partial);
    hipLaunchKernelGGL(final_kernel, dim3(NUM_GRAPHS), dim3(256), 0, stream,
                       partial, br, Wl, bl, (float*)d_out);
}